// Round 1
// baseline (1283.228 us; speedup 1.0000x reference)
//
#include <hip/hip_runtime.h>
#include <stdint.h>

// Problem constants (SelfAttentionLayer): x [32,32,32,512] fp32
#define B_ 32
#define N_ 1024   // H*W
#define C_ 512
#define D_ 64     // DQK
#define R_ 8      // query rows per attn block

// bf16 <-> f32 helpers (OCP bf16 = top 16 bits of f32, RNE)
__device__ inline float b2f(unsigned short u) {
    return __uint_as_float(((unsigned)u) << 16);
}
__device__ inline unsigned short f2b(float f) {
    unsigned u = __float_as_uint(f);
    u += 0x7FFF + ((u >> 16) & 1);   // round-to-nearest-even
    return (unsigned short)(u >> 16);
}

// ---------------------------------------------------------------------------
// Kernel 1: fused QKV projection.  Y[32768, 640] = X[32768,512] @ [wq|wk|wv] + b
// Classic 64x64 tile, BK=16, 4x4 micro-tile per thread. Outputs bf16 to ws.
// grid = (512 row-blocks, 10 col-blocks), block = 256
// ---------------------------------------------------------------------------
__global__ __launch_bounds__(256) void qkv_proj(
    const float* __restrict__ x,
    const float* __restrict__ wq, const float* __restrict__ bq,
    const float* __restrict__ wk, const float* __restrict__ bk,
    const float* __restrict__ wv, const float* __restrict__ bv,
    unsigned short* __restrict__ q, unsigned short* __restrict__ k,
    unsigned short* __restrict__ v)
{
    const int rb = blockIdx.x;   // 64-token row block
    const int cb = blockIdx.y;   // 64-col block: 0=q, 1=k, 2..9=v
    const float* w; const float* bias; int wld, col0, old;
    unsigned short* outp;
    if (cb == 0)      { w = wq; bias = bq; wld = D_; col0 = 0;           outp = q; old = D_; }
    else if (cb == 1) { w = wk; bias = bk; wld = D_; col0 = 0;           outp = k; old = D_; }
    else              { w = wv; bias = bv; wld = C_; col0 = (cb-2)*64;   outp = v; old = C_; }

    __shared__ float xs[16][68];   // [k][row], padded: conflict-free r/w
    __shared__ float ws_[16][64];  // [k][col]

    const int tid = threadIdx.x;
    const int rt = tid >> 4;       // 0..15
    const int ct = tid & 15;       // 0..15
    const int r0 = rt * 4, c0 = ct * 4;
    const int row_base = rb * 64;

    float acc[4][4] = {};

    for (int kk = 0; kk < C_; kk += 16) {
        {   // stage X tile transposed: xs[kcol][row]
            int lc = tid & 15;         // k col
            int lr = tid >> 4;         // row, step 16
            #pragma unroll
            for (int i = 0; i < 4; ++i) {
                int rr = lr + 16 * i;
                xs[lc][rr] = x[(size_t)(row_base + rr) * C_ + kk + lc];
            }
        }
        {   // stage W tile: ws_[krow][col]
            int lcol = tid & 63;
            int lrow = tid >> 6;       // 0..3, step 4
            #pragma unroll
            for (int i = 0; i < 4; ++i) {
                int krow = lrow + 4 * i;
                ws_[krow][lcol] = w[(size_t)(kk + krow) * wld + col0 + lcol];
            }
        }
        __syncthreads();
        #pragma unroll
        for (int kq = 0; kq < 16; ++kq) {
            float4 a = *(const float4*)&xs[kq][r0];
            float4 bb = *(const float4*)&ws_[kq][c0];
            float av[4] = {a.x, a.y, a.z, a.w};
            float bv4[4] = {bb.x, bb.y, bb.z, bb.w};
            #pragma unroll
            for (int i = 0; i < 4; ++i)
                #pragma unroll
                for (int j = 0; j < 4; ++j)
                    acc[i][j] += av[i] * bv4[j];
        }
        __syncthreads();
    }

    const float b0 = bias[col0 + c0 + 0], b1 = bias[col0 + c0 + 1];
    const float b2 = bias[col0 + c0 + 2], b3 = bias[col0 + c0 + 3];
    #pragma unroll
    for (int i = 0; i < 4; ++i) {
        int row = row_base + r0 + i;
        ushort4 o;
        o.x = f2b(acc[i][0] + b0);
        o.y = f2b(acc[i][1] + b1);
        o.z = f2b(acc[i][2] + b2);
        o.w = f2b(acc[i][3] + b3);
        *(ushort4*)&outp[(size_t)row * old + col0 + c0] = o;
    }
}

// ---------------------------------------------------------------------------
// Kernel 2: attention for one (batch, 8 query rows).
// Phase 1: scores[8][1024] (fp32 in LDS) from q·k^T, K staged in 64-row tiles.
// Phase 2: per-wave softmax (wave w owns rows w, w+4).
// Phase 3: P@V with coalesced bf16 V loads + residual, fp32 out.
// grid = (128 tiles, 32 batches), block = 256.  LDS = 52,480 B.
// ---------------------------------------------------------------------------
__global__ __launch_bounds__(256) void attn(
    const unsigned short* __restrict__ q,
    const unsigned short* __restrict__ k,
    const unsigned short* __restrict__ v,
    const float* __restrict__ x,
    float* __restrict__ out)
{
    const int tile = blockIdx.x;   // 0..127
    const int b    = blockIdx.y;   // 0..31
    const int n0   = tile * R_;
    const int tid  = threadIdx.x;
    const int lane = tid & 63;
    const int wave = tid >> 6;

    __shared__ float s_lds[R_][1028];   // scores/probs, stride 1028 (pad)
    __shared__ float q_lds[R_][68];
    __shared__ float k_lds[64][68];

    // stage q rows (threads 0..127)
    if (tid < R_ * 16) {
        int r = tid >> 4, d0 = (tid & 15) * 4;
        const unsigned short* qp = q + ((size_t)(b * N_ + n0 + r)) * D_ + d0;
        float4 f;
        f.x = b2f(qp[0]); f.y = b2f(qp[1]); f.z = b2f(qp[2]); f.w = b2f(qp[3]);
        *(float4*)&q_lds[r][d0] = f;
    }

    // ---- phase 1: scores ----
    const float scale = 0.125f;          // 1/sqrt(64)
    const int r  = tid & 7;
    const int mg = tid >> 3;             // 0..31 -> m pair
    for (int mt = 0; mt < 16; ++mt) {
        const int m0 = mt * 64;
        __syncthreads();                 // k_lds free (also covers q load, iter 0)
        {   // stage K tile: k_lds[mlocal][d]
            int ml = tid >> 2;           // 0..63
            int d0 = (tid & 3) * 16;     // 0,16,32,48
            const unsigned short* kp = k + ((size_t)(b * N_ + m0 + ml)) * D_ + d0;
            #pragma unroll
            for (int j = 0; j < 16; j += 4) {
                float4 f;
                f.x = b2f(kp[j+0]); f.y = b2f(kp[j+1]);
                f.z = b2f(kp[j+2]); f.w = b2f(kp[j+3]);
                *(float4*)&k_lds[ml][d0 + j] = f;
            }
        }
        __syncthreads();
        float acc0 = 0.f, acc1 = 0.f;
        #pragma unroll
        for (int d = 0; d < 64; d += 4) {
            float4 qv = *(const float4*)&q_lds[r][d];
            float4 k0 = *(const float4*)&k_lds[mg*2 + 0][d];
            float4 k1 = *(const float4*)&k_lds[mg*2 + 1][d];
            acc0 += qv.x*k0.x + qv.y*k0.y + qv.z*k0.z + qv.w*k0.w;
            acc1 += qv.x*k1.x + qv.y*k1.y + qv.z*k1.z + qv.w*k1.w;
        }
        s_lds[r][m0 + mg*2 + 0] = acc0 * scale;
        s_lds[r][m0 + mg*2 + 1] = acc1 * scale;
    }
    __syncthreads();

    // ---- phase 2: softmax, wave w -> rows w, w+4 ----
    for (int rr = wave; rr < R_; rr += 4) {
        float vals[16];
        float mx = -1e30f;
        #pragma unroll
        for (int j = 0; j < 16; ++j) {
            vals[j] = s_lds[rr][lane + 64*j];
            mx = fmaxf(mx, vals[j]);
        }
        #pragma unroll
        for (int off = 32; off > 0; off >>= 1) mx = fmaxf(mx, __shfl_xor(mx, off));
        float sum = 0.f;
        #pragma unroll
        for (int j = 0; j < 16; ++j) { vals[j] = __expf(vals[j] - mx); sum += vals[j]; }
        #pragma unroll
        for (int off = 32; off > 0; off >>= 1) sum += __shfl_xor(sum, off);
        float inv = 1.f / sum;
        #pragma unroll
        for (int j = 0; j < 16; ++j) s_lds[rr][lane + 64*j] = vals[j] * inv;
    }
    __syncthreads();

    // ---- phase 3: attended = P @ V, + residual ----
    {
        const int c0 = (tid & 127) * 4;      // 0..508
        const int rg = (tid >> 7) * 4;       // rows rg..rg+3
        float acc[4][4] = {};
        const unsigned short* vb = v + (size_t)b * N_ * C_;
        for (int m = 0; m < N_; ++m) {
            ushort4 vv = *(const ushort4*)(vb + (size_t)m * C_ + c0);
            float v0 = b2f(vv.x), v1 = b2f(vv.y), v2 = b2f(vv.z), v3 = b2f(vv.w);
            #pragma unroll
            for (int i = 0; i < 4; ++i) {
                float p = s_lds[rg + i][m];
                acc[i][0] += p * v0; acc[i][1] += p * v1;
                acc[i][2] += p * v2; acc[i][3] += p * v3;
            }
        }
        #pragma unroll
        for (int i = 0; i < 4; ++i) {
            size_t base = ((size_t)(b * N_ + n0 + rg + i)) * C_ + c0;
            float4 xr = *(const float4*)&x[base];
            float4 o;
            o.x = acc[i][0] + xr.x; o.y = acc[i][1] + xr.y;
            o.z = acc[i][2] + xr.z; o.w = acc[i][3] + xr.w;
            *(float4*)&out[base] = o;
        }
    }
}

// ---------------------------------------------------------------------------
extern "C" void kernel_launch(void* const* d_in, const int* in_sizes, int n_in,
                              void* d_out, int out_size, void* d_ws, size_t ws_size,
                              hipStream_t stream) {
    (void)in_sizes; (void)n_in; (void)out_size;
    const float* x  = (const float*)d_in[0];
    const float* wq = (const float*)d_in[1];
    const float* bq = (const float*)d_in[2];
    const float* wk = (const float*)d_in[3];
    const float* bk = (const float*)d_in[4];
    const float* wv = (const float*)d_in[5];
    const float* bv = (const float*)d_in[6];
    float* out = (float*)d_out;

    // workspace: q (4MB) | k (4MB) | v (33.5MB) as bf16 — needs ws >= 42MB
    unsigned short* qb = (unsigned short*)d_ws;
    unsigned short* kb = qb + (size_t)B_ * N_ * D_;
    unsigned short* vb = kb + (size_t)B_ * N_ * D_;
    (void)ws_size;

    qkv_proj<<<dim3(512, 10), 256, 0, stream>>>(x, wq, bq, wk, bk, wv, bv, qb, kb, vb);
    attn<<<dim3(128, 32), 256, 0, stream>>>(qb, kb, vb, x, out);
}

// Round 2
// 335.593 us; speedup vs baseline: 3.8238x; 3.8238x over previous
//
#include <hip/hip_runtime.h>
#include <stdint.h>

// SelfAttentionLayer: x [32,32,32,512] fp32 -> out fp32 same shape
#define B_ 32
#define N_ 1024   // tokens per batch (H*W)
#define C_ 512
#define D_ 64     // DQK

typedef __attribute__((ext_vector_type(8))) __bf16 bf8;   // MFMA A/B frag (4 VGPRs)
typedef __attribute__((ext_vector_type(4))) float f32x4;  // MFMA C/D frag

typedef const __attribute__((address_space(1))) void* gp_t;
typedef __attribute__((address_space(3))) void* lp_t;

__device__ inline void g2l16(const void* g, void* l) {
    // async global->LDS, 16B/lane; LDS dest = uniform base + lane*16
    __builtin_amdgcn_global_load_lds((gp_t)g, (lp_t)l, 16, 0, 0);
}

__device__ inline unsigned short f2b(float f) {   // f32 -> bf16 bits, RNE
    unsigned u = __float_as_uint(f);
    u += 0x7FFF + ((u >> 16) & 1);
    return (unsigned short)(u >> 16);
}

#define MFMA16(a, b, c) __builtin_amdgcn_mfma_f32_16x16x32_bf16((a), (b), (c), 0, 0, 0)

// ---------------------------------------------------------------------------
// Kernel 0: x fp32 -> bf16 (so qkv can stage via global_load_lds)
// ---------------------------------------------------------------------------
__global__ __launch_bounds__(256) void xcvt(const float* __restrict__ x,
                                            unsigned short* __restrict__ xb) {
    int i = blockIdx.x * 256 + threadIdx.x;      // quad index, exact grid
    float4 f = ((const float4*)x)[i];
    ushort4 o;
    o.x = f2b(f.x); o.y = f2b(f.y); o.z = f2b(f.z); o.w = f2b(f.w);
    ((ushort4*)xb)[i] = o;
}

// ---------------------------------------------------------------------------
// Kernel 0b: weight transpose + cvt: w[cin=512][cout] f32 -> wt[cout][512] bf16
// ---------------------------------------------------------------------------
__global__ __launch_bounds__(256) void wtrans(const float* __restrict__ w,
                                              unsigned short* __restrict__ wt,
                                              int cout) {
    int t = blockIdx.x * 256 + threadIdx.x;      // output-linear, exact grid
    int co = t >> 9;          // /512
    int ci = t & 511;
    wt[t] = f2b(w[(size_t)ci * cout + co]);
}

// ---------------------------------------------------------------------------
// Kernel 1: QKV projection GEMM.  [32768,512]bf16 @ WT -> q,k [tok][64] bf16,
// v written transposed vT[b][c][n] bf16.  Block tile 128x64, waves 2x2 (64x32).
// grid = (256 rowblocks, 10 colblocks: 0=q,1=k,2..9=v)
// ---------------------------------------------------------------------------
__global__ __launch_bounds__(256) void qkv(
    const unsigned short* __restrict__ xb,
    const unsigned short* __restrict__ wqT,
    const unsigned short* __restrict__ wkT,
    const unsigned short* __restrict__ wvT,
    const float* __restrict__ bq, const float* __restrict__ bk,
    const float* __restrict__ bv,
    unsigned short* __restrict__ q, unsigned short* __restrict__ k,
    unsigned short* __restrict__ vT)
{
    const int rb = blockIdx.x;
    const int cb = blockIdx.y;
    const int tid = threadIdx.x;
    const int lane = tid & 63;
    const int wave = tid >> 6;
    const int wm = wave >> 1, wn = wave & 1;
    const int lr = lane & 15;     // frag row/col within 16
    const int lk = lane >> 4;     // k-octet 0..3

    __shared__ unsigned short As[128 * 64];   // fragment-order: 16 frags x 512 elems
    __shared__ unsigned short TB[64 * 132];   // v transpose buffer (pad 132)

    const unsigned short* wt; const float* bias; int colbase;
    if (cb == 0)      { wt = wqT; bias = bq; colbase = 0; }
    else if (cb == 1) { wt = wkT; bias = bk; colbase = 0; }
    else              { wt = wvT; bias = bv; colbase = (cb - 2) * 64; }

    const int row0 = rb * 128;

    f32x4 zero4 = {0.f, 0.f, 0.f, 0.f};
    f32x4 acc[4][2];
    #pragma unroll
    for (int i = 0; i < 4; ++i) { acc[i][0] = zero4; acc[i][1] = zero4; }

    for (int kk = 0; kk < C_; kk += 64) {
        __syncthreads();
        #pragma unroll
        for (int i = 0; i < 4; ++i) {          // 16 A-frags, 4 per wave
            int f = wave * 4 + i;
            int ti = f >> 1, kq = f & 1;
            const unsigned short* g = xb + (size_t)(row0 + ti * 16 + lr) * C_
                                         + kk + kq * 32 + lk * 8;
            g2l16(g, &As[f * 512]);
        }
        __syncthreads();                        // drains vmcnt -> data ready
        #pragma unroll
        for (int kq = 0; kq < 2; ++kq) {
            bf8 a[4];
            #pragma unroll
            for (int ti = 0; ti < 4; ++ti)
                a[ti] = *(const bf8*)&As[(((wm * 4 + ti) * 2) + kq) * 512 + lane * 8];
            bf8 bb[2];
            #pragma unroll
            for (int tj = 0; tj < 2; ++tj)
                bb[tj] = *(const bf8*)&wt[(size_t)(colbase + wn * 32 + tj * 16 + lr) * C_
                                          + kk + kq * 32 + lk * 8];
            #pragma unroll
            for (int ti = 0; ti < 4; ++ti)
                #pragma unroll
                for (int tj = 0; tj < 2; ++tj)
                    acc[ti][tj] = MFMA16(a[ti], bb[tj], acc[ti][tj]);
        }
    }

    if (cb < 2) {
        unsigned short* outp = (cb == 0) ? q : k;
        #pragma unroll
        for (int ti = 0; ti < 4; ++ti)
            #pragma unroll
            for (int tj = 0; tj < 2; ++tj) {
                int col = wn * 32 + tj * 16 + lr;
                float bi = bias[col];
                #pragma unroll
                for (int r = 0; r < 4; ++r) {
                    int row = row0 + wm * 64 + ti * 16 + lk * 4 + r;
                    outp[(size_t)row * D_ + col] = f2b(acc[ti][tj][r] + bi);
                }
            }
    } else {
        __syncthreads();                        // As reads done; TB distinct anyway
        #pragma unroll
        for (int ti = 0; ti < 4; ++ti)
            #pragma unroll
            for (int tj = 0; tj < 2; ++tj) {
                int c = wn * 32 + tj * 16 + lr;         // 0..63 within block
                float bi = bias[colbase + c];
                int tok = wm * 64 + ti * 16 + lk * 4;   // 0..124 (4 consecutive)
                ushort4 o;
                o.x = f2b(acc[ti][tj][0] + bi);
                o.y = f2b(acc[ti][tj][1] + bi);
                o.z = f2b(acc[ti][tj][2] + bi);
                o.w = f2b(acc[ti][tj][3] + bi);
                *(ushort4*)&TB[c * 132 + tok] = o;
            }
        __syncthreads();
        const int b  = row0 >> 10;
        const int n0 = row0 & 1023;
        #pragma unroll
        for (int i = 0; i < 8; ++i) {
            int idx = tid + 256 * i;                    // 0..2047
            int c = idx >> 5, ch = idx & 31;
            ushort4 t4 = *(const ushort4*)&TB[c * 132 + ch * 4];
            *(ushort4*)&vT[((size_t)b * C_ + colbase + c) * N_ + n0 + ch * 4] = t4;
        }
    }
}

// ---------------------------------------------------------------------------
// Kernel 2: scores + softmax -> P bf16 [b][n][m].
// Block: one batch, 16 query rows. Waves split m (256 each). S strip in LDS.
// grid = (64 qtiles, 32 batches)
// ---------------------------------------------------------------------------
__global__ __launch_bounds__(256) void scores(
    const unsigned short* __restrict__ q,
    const unsigned short* __restrict__ k,
    unsigned short* __restrict__ P)
{
    const int qt = blockIdx.x, b = blockIdx.y;
    const int tid = threadIdx.x, lane = tid & 63, wave = tid >> 6;
    const int lr = lane & 15, lk = lane >> 4;
    __shared__ float S[16 * 1024];              // 64 KB

    const int n0 = qt * 16;
    const unsigned short* qrow = q + (size_t)(b * N_ + n0 + lr) * D_ + lk * 8;
    bf8 qa0 = *(const bf8*)(qrow);
    bf8 qa1 = *(const bf8*)(qrow + 32);

    const int m0w = wave * 256;
    for (int mt = 0; mt < 16; ++mt) {
        int m = m0w + mt * 16;
        const unsigned short* krow = k + (size_t)(b * N_ + m + lr) * D_ + lk * 8;
        bf8 kb0 = *(const bf8*)(krow);
        bf8 kb1 = *(const bf8*)(krow + 32);
        f32x4 s = {0.f, 0.f, 0.f, 0.f};
        s = MFMA16(qa0, kb0, s);
        s = MFMA16(qa1, kb1, s);
        #pragma unroll
        for (int r = 0; r < 4; ++r)
            S[(lk * 4 + r) * 1024 + m + lr] = s[r] * 0.125f;   // 1/sqrt(64)
    }
    __syncthreads();

    #pragma unroll
    for (int rr4 = 0; rr4 < 4; ++rr4) {
        int rr = wave * 4 + rr4;
        float vals[16];
        float mx = -1e30f;
        #pragma unroll
        for (int j = 0; j < 16; ++j) {
            vals[j] = S[rr * 1024 + j * 64 + lane];
            mx = fmaxf(mx, vals[j]);
        }
        #pragma unroll
        for (int off = 32; off; off >>= 1) mx = fmaxf(mx, __shfl_xor(mx, off));
        float sum = 0.f;
        #pragma unroll
        for (int j = 0; j < 16; ++j) { vals[j] = __expf(vals[j] - mx); sum += vals[j]; }
        #pragma unroll
        for (int off = 32; off; off >>= 1) sum += __shfl_xor(sum, off);
        float inv = 1.f / sum;
        unsigned short* pp = P + (size_t)(b * N_ + n0 + rr) * N_;
        #pragma unroll
        for (int j = 0; j < 16; ++j) pp[j * 64 + lane] = f2b(vals[j] * inv);
    }
}

// ---------------------------------------------------------------------------
// Kernel 3: O = P @ V + x (residual), fp32 out. Per-batch GEMM M=1024 N=512
// K=1024. Block tile 128x128, waves 2x2 (64x64 each), BK=64, both operands
// staged fragment-order via global_load_lds.  grid = (8, 4, 32)
// ---------------------------------------------------------------------------
__global__ __launch_bounds__(256) void pv(
    const unsigned short* __restrict__ P,
    const unsigned short* __restrict__ vT,
    const float* __restrict__ x,
    float* __restrict__ out)
{
    const int m0 = blockIdx.x * 128, c0 = blockIdx.y * 128, b = blockIdx.z;
    const int tid = threadIdx.x, lane = tid & 63, wave = tid >> 6;
    const int wm = wave >> 1, wn = wave & 1;
    const int lr = lane & 15, lk = lane >> 4;

    __shared__ unsigned short As[128 * 64];   // P frags
    __shared__ unsigned short Bs[128 * 64];   // V frags

    f32x4 zero4 = {0.f, 0.f, 0.f, 0.f};
    f32x4 acc[4][4];
    #pragma unroll
    for (int i = 0; i < 4; ++i)
        #pragma unroll
        for (int j = 0; j < 4; ++j) acc[i][j] = zero4;

    const unsigned short* Pb = P  + (size_t)b * N_ * N_;
    const unsigned short* Vb = vT + (size_t)b * C_ * N_;

    for (int kk = 0; kk < N_; kk += 64) {
        __syncthreads();
        #pragma unroll
        for (int i = 0; i < 4; ++i) {
            int f = wave * 4 + i;
            int t = f >> 1, kq = f & 1;
            g2l16(Pb + (size_t)(m0 + t * 16 + lr) * N_ + kk + kq * 32 + lk * 8,
                  &As[f * 512]);
            g2l16(Vb + (size_t)(c0 + t * 16 + lr) * N_ + kk + kq * 32 + lk * 8,
                  &Bs[f * 512]);
        }
        __syncthreads();
        #pragma unroll
        for (int kq = 0; kq < 2; ++kq) {
            bf8 a[4], bb[4];
            #pragma unroll
            for (int ti = 0; ti < 4; ++ti)
                a[ti] = *(const bf8*)&As[((wm * 4 + ti) * 2 + kq) * 512 + lane * 8];
            #pragma unroll
            for (int tj = 0; tj < 4; ++tj)
                bb[tj] = *(const bf8*)&Bs[((wn * 4 + tj) * 2 + kq) * 512 + lane * 8];
            #pragma unroll
            for (int ti = 0; ti < 4; ++ti)
                #pragma unroll
                for (int tj = 0; tj < 4; ++tj)
                    acc[ti][tj] = MFMA16(a[ti], bb[tj], acc[ti][tj]);
        }
    }

    #pragma unroll
    for (int ti = 0; ti < 4; ++ti)
        #pragma unroll
        for (int tj = 0; tj < 4; ++tj) {
            int col = c0 + wn * 64 + tj * 16 + lr;
            #pragma unroll
            for (int r = 0; r < 4; ++r) {
                int row = m0 + wm * 64 + ti * 16 + lk * 4 + r;
                size_t idx = (size_t)(b * N_ + row) * C_ + col;
                out[idx] = acc[ti][tj][r] + x[idx];
            }
        }
}

// ---------------------------------------------------------------------------
extern "C" void kernel_launch(void* const* d_in, const int* in_sizes, int n_in,
                              void* d_out, int out_size, void* d_ws, size_t ws_size,
                              hipStream_t stream) {
    (void)in_sizes; (void)n_in; (void)out_size; (void)ws_size;
    const float* xf = (const float*)d_in[0];
    const float* wq = (const float*)d_in[1];
    const float* bq = (const float*)d_in[2];
    const float* wk = (const float*)d_in[3];
    const float* bk = (const float*)d_in[4];
    const float* wv = (const float*)d_in[5];
    const float* bv = (const float*)d_in[6];
    float* out = (float*)d_out;

    // workspace layout (bytes), total needed ~109,051,904 (104 MB):
    //   q   [0, 4MB) | k [4MB, 8MB) | vT [8MB, 40MB)
    //   wqT/wkT/wvT + xb in [40MB, 72.6MB)  -- dead after qkv
    //   P (64MB) aliased over wT+xb region starting 41,943,040
    char* ws = (char*)d_ws;
    unsigned short* qb  = (unsigned short*)(ws);
    unsigned short* kb  = (unsigned short*)(ws + 4194304);
    unsigned short* vTb = (unsigned short*)(ws + 8388608);
    unsigned short* wqT = (unsigned short*)(ws + 41943040);
    unsigned short* wkT = (unsigned short*)(ws + 42008576);
    unsigned short* wvT = (unsigned short*)(ws + 42074112);
    unsigned short* xb  = (unsigned short*)(ws + 42598400);
    unsigned short* Pb  = (unsigned short*)(ws + 41943040);  // overlaps wT+xb

    xcvt<<<16384, 256, 0, stream>>>(xf, xb);                    // 16.7M elems
    wtrans<<<128, 256, 0, stream>>>(wq, wqT, 64);
    wtrans<<<128, 256, 0, stream>>>(wk, wkT, 64);
    wtrans<<<1024, 256, 0, stream>>>(wv, wvT, 512);
    qkv<<<dim3(256, 10), 256, 0, stream>>>(xb, wqT, wkT, wvT, bq, bk, bv,
                                           qb, kb, vTb);
    scores<<<dim3(64, 32), 256, 0, stream>>>(qb, kb, Pb);
    pv<<<dim3(8, 4, 32), 256, 0, stream>>>(Pb, vTb, xf, out);
}

// Round 3
// 294.728 us; speedup vs baseline: 4.3539x; 1.1387x over previous
//
#include <hip/hip_runtime.h>
#include <stdint.h>

// SelfAttentionLayer: x [32,32,32,512] fp32 -> out fp32 same shape
#define B_ 32
#define N_ 1024   // tokens per batch (H*W)
#define C_ 512
#define D_ 64     // DQK

typedef __attribute__((ext_vector_type(8))) __bf16 bf8;   // MFMA A/B frag (4 VGPRs)
typedef __attribute__((ext_vector_type(4))) float f32x4;  // MFMA C/D frag

typedef const __attribute__((address_space(1))) void* gp_t;
typedef __attribute__((address_space(3))) void* lp_t;

__device__ inline void g2l16(const void* g, void* l) {
    // async global->LDS, 16B/lane; LDS dest = uniform base + lane*16
    __builtin_amdgcn_global_load_lds((gp_t)g, (lp_t)l, 16, 0, 0);
}

__device__ inline float b2f(unsigned short u) {
    return __uint_as_float(((unsigned)u) << 16);
}
__device__ inline unsigned short f2b(float f) {   // f32 -> bf16 bits, RNE
    unsigned u = __float_as_uint(f);
    u += 0x7FFF + ((u >> 16) & 1);
    return (unsigned short)(u >> 16);
}

#define MFMA16(a, b, c) __builtin_amdgcn_mfma_f32_16x16x32_bf16((a), (b), (c), 0, 0, 0)

// ---------------------------------------------------------------------------
// Kernel 0: x fp32 -> bf16 (so qkv can stage via global_load_lds)
// ---------------------------------------------------------------------------
__global__ __launch_bounds__(256) void xcvt(const float* __restrict__ x,
                                            unsigned short* __restrict__ xb) {
    int i = blockIdx.x * 256 + threadIdx.x;      // quad index, exact grid
    float4 f = ((const float4*)x)[i];
    ushort4 o;
    o.x = f2b(f.x); o.y = f2b(f.y); o.z = f2b(f.z); o.w = f2b(f.w);
    ((ushort4*)xb)[i] = o;
}

// ---------------------------------------------------------------------------
// Kernel 0b: weight transpose + cvt into concatenated WT[640][512] bf16.
// w[cin=512][cout] f32 -> wt[cout][512].  wt points at the row offset.
// ---------------------------------------------------------------------------
__global__ __launch_bounds__(256) void wtrans(const float* __restrict__ w,
                                              unsigned short* __restrict__ wt,
                                              int cout) {
    int t = blockIdx.x * 256 + threadIdx.x;      // output-linear, exact grid
    int co = t >> 9;          // /512
    int ci = t & 511;
    wt[t] = f2b(w[(size_t)ci * cout + co]);
}

// ---------------------------------------------------------------------------
// Kernel 1: QKV projection GEMM. [32768,512]bf16 @ WT[640,512]^T.
// Block tile 128x128, waves 2x2 (64x64 each), BK=64, both operands staged
// fragment-order via global_load_lds (same structure as pv).
// grid = (256 rowblocks, 5 colblocks): cb 0 -> q|k cols, cb 1..4 -> v cols.
// v written transposed vT[b][c][n] via LDS transpose buffer (aliased).
// ---------------------------------------------------------------------------
__global__ __launch_bounds__(256) void qkv(
    const unsigned short* __restrict__ xb,
    const unsigned short* __restrict__ WT,
    const float* __restrict__ bq, const float* __restrict__ bk,
    const float* __restrict__ bv,
    unsigned short* __restrict__ q, unsigned short* __restrict__ k,
    unsigned short* __restrict__ vT)
{
    const int rb = blockIdx.x;
    const int cb = blockIdx.y;
    const int tid = threadIdx.x;
    const int lane = tid & 63;
    const int wave = tid >> 6;
    const int wm = wave >> 1, wn = wave & 1;
    const int lr = lane & 15;     // frag row/col within 16
    const int lk = lane >> 4;     // k-octet 0..3

    __shared__ unsigned short SM[16896];      // As(16K shorts... see below)
    unsigned short* As = SM;                  // [0, 8192)   128x64 frag-order
    unsigned short* Bs = SM + 8192;           // [8192,16384) 128x64 frag-order
    unsigned short* TB = SM;                  // aliased transpose buf 128x132

    const int row0 = rb * 128;
    const int col0 = cb * 128;                // within [640]

    f32x4 zero4 = {0.f, 0.f, 0.f, 0.f};
    f32x4 acc[4][4];
    #pragma unroll
    for (int i = 0; i < 4; ++i)
        #pragma unroll
        for (int j = 0; j < 4; ++j) acc[i][j] = zero4;

    for (int kk = 0; kk < C_; kk += 64) {
        __syncthreads();
        #pragma unroll
        for (int i = 0; i < 4; ++i) {          // 16 frags each for A and B
            int f = wave * 4 + i;
            int t = f >> 1, kq = f & 1;
            g2l16(xb + (size_t)(row0 + t * 16 + lr) * C_ + kk + kq * 32 + lk * 8,
                  &As[f * 512]);
            g2l16(WT + (size_t)(col0 + t * 16 + lr) * C_ + kk + kq * 32 + lk * 8,
                  &Bs[f * 512]);
        }
        __syncthreads();
        #pragma unroll
        for (int kq = 0; kq < 2; ++kq) {
            bf8 a[4], bb[4];
            #pragma unroll
            for (int ti = 0; ti < 4; ++ti)
                a[ti] = *(const bf8*)&As[((wm * 4 + ti) * 2 + kq) * 512 + lane * 8];
            #pragma unroll
            for (int tj = 0; tj < 4; ++tj)
                bb[tj] = *(const bf8*)&Bs[((wn * 4 + tj) * 2 + kq) * 512 + lane * 8];
            #pragma unroll
            for (int ti = 0; ti < 4; ++ti)
                #pragma unroll
                for (int tj = 0; tj < 4; ++tj)
                    acc[ti][tj] = MFMA16(a[ti], bb[tj], acc[ti][tj]);
        }
    }

    if (cb == 0) {
        // wn==0 waves own cols 0..63 (-> q), wn==1 own cols 64..127 (-> k)
        unsigned short* outp = (wn == 0) ? q : k;
        const float* bias = (wn == 0) ? bq : bk;
        #pragma unroll
        for (int ti = 0; ti < 4; ++ti)
            #pragma unroll
            for (int tj = 0; tj < 4; ++tj) {
                int col = tj * 16 + lr;           // 0..63 within q or k
                float bi = bias[col];
                #pragma unroll
                for (int r = 0; r < 4; ++r) {
                    int row = row0 + wm * 64 + ti * 16 + lk * 4 + r;
                    outp[(size_t)row * D_ + col] = f2b(acc[ti][tj][r] + bi);
                }
            }
    } else {
        const int colv = (cb - 1) * 128;          // v col base (0..511)
        __syncthreads();                          // As/Bs reads done; TB aliases
        #pragma unroll
        for (int ti = 0; ti < 4; ++ti)
            #pragma unroll
            for (int tj = 0; tj < 4; ++tj) {
                int c = wn * 64 + tj * 16 + lr;   // 0..127 within block
                float bi = bv[colv + c];
                int tok = wm * 64 + ti * 16 + lk * 4;
                ushort4 o;
                o.x = f2b(acc[ti][tj][0] + bi);
                o.y = f2b(acc[ti][tj][1] + bi);
                o.z = f2b(acc[ti][tj][2] + bi);
                o.w = f2b(acc[ti][tj][3] + bi);
                *(ushort4*)&TB[c * 132 + tok] = o;
            }
        __syncthreads();
        const int b  = row0 >> 10;
        const int n0 = row0 & 1023;
        #pragma unroll
        for (int i = 0; i < 16; ++i) {
            int idx = tid + 256 * i;              // 0..4095
            int c = idx >> 5, ch = idx & 31;
            ushort4 t4 = *(const ushort4*)&TB[c * 132 + ch * 4];
            *(ushort4*)&vT[((size_t)(b * C_ + colv + c)) * N_ + n0 + ch * 4] = t4;
        }
    }
}

// ---------------------------------------------------------------------------
// Kernel 2: scores + softmax -> P bf16 [b][n][m].
// Block: one batch, 16 query rows. Waves split m (256 each). S strip in LDS
// as bf16 (33 KB incl pad -> 4 blocks/CU).  grid = (64 qtiles, 32 batches)
// ---------------------------------------------------------------------------
#define SLD 1032   // S leading dim (shorts), pad 8 to break 2048B bank period
__global__ __launch_bounds__(256) void scores(
    const unsigned short* __restrict__ q,
    const unsigned short* __restrict__ k,
    unsigned short* __restrict__ P)
{
    const int qt = blockIdx.x, b = blockIdx.y;
    const int tid = threadIdx.x, lane = tid & 63, wave = tid >> 6;
    const int lr = lane & 15, lk = lane >> 4;
    __shared__ unsigned short S[16 * SLD];      // bf16 scores, 33 KB

    const int n0 = qt * 16;
    const unsigned short* qrow = q + (size_t)(b * N_ + n0 + lr) * D_ + lk * 8;
    bf8 qa0 = *(const bf8*)(qrow);
    bf8 qa1 = *(const bf8*)(qrow + 32);

    const int m0w = wave * 256;
    #pragma unroll 4
    for (int mt = 0; mt < 16; ++mt) {
        int m = m0w + mt * 16;
        const unsigned short* krow = k + (size_t)(b * N_ + m + lr) * D_ + lk * 8;
        bf8 kb0 = *(const bf8*)(krow);
        bf8 kb1 = *(const bf8*)(krow + 32);
        f32x4 s = {0.f, 0.f, 0.f, 0.f};
        s = MFMA16(qa0, kb0, s);
        s = MFMA16(qa1, kb1, s);
        #pragma unroll
        for (int r = 0; r < 4; ++r)
            S[(lk * 4 + r) * SLD + m + lr] = f2b(s[r] * 0.125f);  // 1/sqrt(64)
    }
    __syncthreads();

    #pragma unroll
    for (int rr4 = 0; rr4 < 4; ++rr4) {
        int rr = wave * 4 + rr4;
        float vals[16];
        float mx = -1e30f;
        #pragma unroll
        for (int j = 0; j < 16; ++j) {
            vals[j] = b2f(S[rr * SLD + j * 64 + lane]);
            mx = fmaxf(mx, vals[j]);
        }
        #pragma unroll
        for (int off = 32; off; off >>= 1) mx = fmaxf(mx, __shfl_xor(mx, off));
        float sum = 0.f;
        #pragma unroll
        for (int j = 0; j < 16; ++j) { vals[j] = __expf(vals[j] - mx); sum += vals[j]; }
        #pragma unroll
        for (int off = 32; off; off >>= 1) sum += __shfl_xor(sum, off);
        float inv = 1.f / sum;
        unsigned short* pp = P + (size_t)(b * N_ + n0 + rr) * N_;
        #pragma unroll
        for (int j = 0; j < 16; ++j) pp[j * 64 + lane] = f2b(vals[j] * inv);
    }
}

// ---------------------------------------------------------------------------
// Kernel 3: O = P @ V + x (residual), fp32 out. Per-batch GEMM M=1024 N=512
// K=1024. Block tile 128x128, waves 2x2, BK=64, both operands staged
// fragment-order via global_load_lds.  grid = (8, 4, 32)
// ---------------------------------------------------------------------------
__global__ __launch_bounds__(256) void pv(
    const unsigned short* __restrict__ P,
    const unsigned short* __restrict__ vT,
    const float* __restrict__ x,
    float* __restrict__ out)
{
    const int m0 = blockIdx.x * 128, c0 = blockIdx.y * 128, b = blockIdx.z;
    const int tid = threadIdx.x, lane = tid & 63, wave = tid >> 6;
    const int wm = wave >> 1, wn = wave & 1;
    const int lr = lane & 15, lk = lane >> 4;

    __shared__ unsigned short As[128 * 64];   // P frags
    __shared__ unsigned short Bs[128 * 64];   // V frags

    f32x4 zero4 = {0.f, 0.f, 0.f, 0.f};
    f32x4 acc[4][4];
    #pragma unroll
    for (int i = 0; i < 4; ++i)
        #pragma unroll
        for (int j = 0; j < 4; ++j) acc[i][j] = zero4;

    const unsigned short* Pb = P  + (size_t)b * N_ * N_;
    const unsigned short* Vb = vT + (size_t)b * C_ * N_;

    for (int kk = 0; kk < N_; kk += 64) {
        __syncthreads();
        #pragma unroll
        for (int i = 0; i < 4; ++i) {
            int f = wave * 4 + i;
            int t = f >> 1, kq = f & 1;
            g2l16(Pb + (size_t)(m0 + t * 16 + lr) * N_ + kk + kq * 32 + lk * 8,
                  &As[f * 512]);
            g2l16(Vb + (size_t)(c0 + t * 16 + lr) * N_ + kk + kq * 32 + lk * 8,
                  &Bs[f * 512]);
        }
        __syncthreads();
        #pragma unroll
        for (int kq = 0; kq < 2; ++kq) {
            bf8 a[4], bb[4];
            #pragma unroll
            for (int ti = 0; ti < 4; ++ti)
                a[ti] = *(const bf8*)&As[((wm * 4 + ti) * 2 + kq) * 512 + lane * 8];
            #pragma unroll
            for (int tj = 0; tj < 4; ++tj)
                bb[tj] = *(const bf8*)&Bs[((wn * 4 + tj) * 2 + kq) * 512 + lane * 8];
            #pragma unroll
            for (int ti = 0; ti < 4; ++ti)
                #pragma unroll
                for (int tj = 0; tj < 4; ++tj)
                    acc[ti][tj] = MFMA16(a[ti], bb[tj], acc[ti][tj]);
        }
    }

    #pragma unroll
    for (int ti = 0; ti < 4; ++ti)
        #pragma unroll
        for (int tj = 0; tj < 4; ++tj) {
            int col = c0 + wn * 64 + tj * 16 + lr;
            #pragma unroll
            for (int r = 0; r < 4; ++r) {
                int row = m0 + wm * 64 + ti * 16 + lk * 4 + r;
                size_t idx = (size_t)(b * N_ + row) * C_ + col;
                out[idx] = acc[ti][tj][r] + x[idx];
            }
        }
}

// ---------------------------------------------------------------------------
extern "C" void kernel_launch(void* const* d_in, const int* in_sizes, int n_in,
                              void* d_out, int out_size, void* d_ws, size_t ws_size,
                              hipStream_t stream) {
    (void)in_sizes; (void)n_in; (void)out_size; (void)ws_size;
    const float* xf = (const float*)d_in[0];
    const float* wq = (const float*)d_in[1];
    const float* bq = (const float*)d_in[2];
    const float* wk = (const float*)d_in[3];
    const float* bk = (const float*)d_in[4];
    const float* wv = (const float*)d_in[5];
    const float* bv = (const float*)d_in[6];
    float* out = (float*)d_out;

    // workspace layout (bytes), total needed ~109 MB:
    //   q [0,4MB) | k [4MB,8MB) | vT [8MB,40MB)
    //   WT (655KB) + xb (32MB) in [40MB, 76MB)  -- dead after qkv
    //   P (64MB) aliased over WT+xb region starting 41,943,040
    char* ws = (char*)d_ws;
    unsigned short* qb  = (unsigned short*)(ws);
    unsigned short* kb  = (unsigned short*)(ws + 4194304);
    unsigned short* vTb = (unsigned short*)(ws + 8388608);
    unsigned short* WT  = (unsigned short*)(ws + 41943040);  // [640][512]
    unsigned short* xb  = (unsigned short*)(ws + 42598400);
    unsigned short* Pb  = (unsigned short*)(ws + 41943040);  // overlaps WT+xb

    xcvt<<<16384, 256, 0, stream>>>(xf, xb);                 // 16.7M elems
    wtrans<<<128, 256, 0, stream>>>(wq, WT, 64);             // rows 0..63
    wtrans<<<128, 256, 0, stream>>>(wk, WT + 64 * 512, 64);  // rows 64..127
    wtrans<<<1024, 256, 0, stream>>>(wv, WT + 128 * 512, 512); // rows 128..639
    qkv<<<dim3(256, 5), 256, 0, stream>>>(xb, WT, bq, bk, bv, qb, kb, vTb);
    scores<<<dim3(64, 32), 256, 0, stream>>>(qb, kb, Pb);
    pv<<<dim3(8, 4, 32), 256, 0, stream>>>(Pb, vTb, xf, out);
}